// Round 2
// baseline (6151.394 us; speedup 1.0000x reference)
//
#include <hip/hip_runtime.h>
#include <hip/hip_bf16.h>
#include <math.h>

#define N_NODES 5000
#define N_STRUCT 50
#define PER 100
#define K_NB 24
#define N_EDGES (N_NODES*K_NB)
#define TMAX 32
#define D 128
#define FF 512
#define NTOK (N_NODES*TMAX)

__device__ __forceinline__ float gelu_f(float x){
    float x3 = x*x*x;
    float t = tanhf(0.7978845608028654f*(x + 0.044715f*x3));
    return 0.5f*x*(1.f+t);
}

__device__ __forceinline__ float cutoff_f(float r){
    if (r < 3.f) return 1.f;
    if (r >= 5.f) return 0.f;
    float x = (r-3.f)*0.5f;
    return 0.5f*(1.f + cosf(3.14159265358979323846f * x));
}

__global__ void k_elem(const int* __restrict__ numbers, int* __restrict__ ELEM){
    int i = blockIdx.x*256 + threadIdx.x;
    if (i < N_NODES){
        int z = numbers[i];
        ELEM[i] = (z==1)?0:(z==6)?1:(z==7)?2:(z==8)?3:-1;
    }
}

// Precontract encoder weights: W3 = Wcart@Wcomp[0:128], ECn = embC@Wcomp[128:256], ENn = embN@Wcomp[256:384]
__global__ void k_prep(const float* __restrict__ Wcart, const float* __restrict__ embc,
                       const float* __restrict__ embn, const float* __restrict__ Wcomp,
                       float* __restrict__ W3, float* __restrict__ ECn, float* __restrict__ ENn){
    int j = threadIdx.x; // 128
    for (int a = 0; a < 3; a++){
        float s = 0;
        for (int i = 0; i < 128; i++) s += Wcart[a*128+i]*Wcomp[i*128+j];
        W3[a*128+j] = s;
    }
    for (int sp = 0; sp < 4; sp++){
        float s1 = 0, s2 = 0;
        for (int i = 0; i < 128; i++){
            s1 += embc[sp*128+i]*Wcomp[(128+i)*128+j];
            s2 += embn[sp*128+i]*Wcomp[(256+i)*128+j];
        }
        ECn[sp*128+j] = s1; ENn[sp*128+j] = s2;
    }
}

__global__ void k_edge(const float* __restrict__ pos, const float* __restrict__ cells,
                       const float* __restrict__ shifts, const int* __restrict__ centers,
                       const int* __restrict__ neighbors, float* __restrict__ EV,
                       float* __restrict__ RAD, int* __restrict__ CORR){
    int e = blockIdx.x*256 + threadIdx.x;
    if (e >= N_EDGES) return;
    int c = centers[e], nb = neighbors[e];
    int st = c / PER;
    const float* cell = cells + st*9;
    float s0 = shifts[e*3+0], s1 = shifts[e*3+1], s2 = shifts[e*3+2];
    float ex = pos[nb*3+0]-pos[c*3+0] + s0*cell[0]+s1*cell[3]+s2*cell[6];
    float ey = pos[nb*3+1]-pos[c*3+1] + s0*cell[1]+s1*cell[4]+s2*cell[7];
    float ez = pos[nb*3+2]-pos[c*3+2] + s0*cell[2]+s1*cell[5]+s2*cell[8];
    EV[e*3+0] = ex; EV[e*3+1] = ey; EV[e*3+2] = ez;
    RAD[e] = cutoff_f(sqrtf(ex*ex+ey*ey+ez*ez));
    // reverse edge search (graph symmetric, 24 edges per center, centers sorted)
    int base = nb*K_NB, corr = base;
    for (int k2 = 0; k2 < K_NB; k2++){
        if (neighbors[base+k2] == c){ corr = base+k2; break; }
    }
    CORR[e] = corr;
}

__global__ void k_encode(const float* __restrict__ EV, const float* __restrict__ RAD,
                         const int* __restrict__ centers, const int* __restrict__ neighbors,
                         const int* __restrict__ ELEM, const float* __restrict__ W3,
                         const float* __restrict__ ECn, const float* __restrict__ ENn,
                         float* __restrict__ X, float* __restrict__ RADN){
    int row = blockIdx.x;   // 0..NTOK-1
    int j = threadIdx.x;    // 0..127
    int n = row >> 5, s = row & 31;
    int e = (s < K_NB) ? (n*K_NB + s) : 0;   // padding slots replicate edge 0 (nef_idx=0)
    int ec = ELEM[centers[e]], en = ELEM[neighbors[e]];
    float ev0 = EV[e*3+0], ev1 = EV[e*3+1], ev2 = EV[e*3+2];
    float v = ev0*W3[j] + ev1*W3[128+j] + ev2*W3[256+j] + ECn[ec*128+j] + ENn[en*128+j];
    X[(size_t)row*D + j] = v;
    if (j == 0) RADN[row] = (s < K_NB) ? RAD[e] : 0.f;
}

// Fused attention block, 3 LDS buffers (50688 B):
//   B0: hs(LN out) -> v*rad (in-place, per-wave rows)
//   B1: x staging  -> q -> probs (swizzled [4][32][32])
//   B2: k -> raw scores [4][32][33] -> attn_out
__global__ __launch_bounds__(256) void k_attn(float* __restrict__ X,
        const float* __restrict__ Wq, const float* __restrict__ Wk,
        const float* __restrict__ Wv, const float* __restrict__ Wo,
        const float* __restrict__ lnw, const float* __restrict__ lnb,
        const float* __restrict__ radn){
    __shared__ float B0[32][132];
    __shared__ float B1[32][132];
    __shared__ float B2[32][132];

    const int n = blockIdx.x;
    const int tid = threadIdx.x;
    const int lane = tid & 63;
    const int wv = tid >> 6;
    const int j0 = lane, t0 = wv*8;
    float* Xn = X + (size_t)n * 32 * D;

    // stage X -> B1 (coalesced float4)
    for (int idx = tid; idx < 32*32; idx += 256){
        int r = idx >> 5, c4 = idx & 31;
        *(float4*)&B1[r][c4*4] = ((const float4*)Xn)[idx];
    }
    __syncthreads();

    // residual stash in regs (own rows, 2-way LDS reads)
    float resA[8], resB[8];
    #pragma unroll
    for (int t = 0; t < 8; t++){ resA[t] = B1[t0+t][j0]; resB[t] = B1[t0+t][j0+64]; }

    {   // LayerNorm: 8 threads/row, rows owned by the thread's wave
        int row = tid >> 3, l8 = tid & 7;
        float s = 0, ss = 0;
        #pragma unroll
        for (int k = 0; k < 16; k++){ float v = B1[row][l8+8*k]; s += v; ss += v*v; }
        #pragma unroll
        for (int m = 1; m < 8; m <<= 1){ s += __shfl_xor(s, m); ss += __shfl_xor(ss, m); }
        float mean = s*(1.f/128.f);
        float rstd = rsqrtf(ss*(1.f/128.f) - mean*mean + 1e-5f);
        #pragma unroll
        for (int k = 0; k < 16; k++){
            int j = l8+8*k;
            B0[row][j] = (B1[row][j]-mean)*rstd*lnw[j] + lnb[j];
        }
    }
    // no barrier needed: QKV below reads only this wave's own B0/B1 rows

    {   // QKV projections: wave owns 8 rows; Q->B1, K->B2, V->B0 in place (rad folded in)
        auto proj = [&](const float* __restrict__ W, float* accA, float* accB){
            #pragma unroll
            for (int t = 0; t < 8; t++){ accA[t]=0.f; accB[t]=0.f; }
            for (int i4 = 0; i4 < 32; i4++){
                float wA[4], wB[4];
                #pragma unroll
                for (int d2 = 0; d2 < 4; d2++){
                    wA[d2] = W[(i4*4+d2)*D + j0];
                    wB[d2] = W[(i4*4+d2)*D + j0+64];
                }
                #pragma unroll
                for (int t = 0; t < 8; t++){
                    float4 h = *(const float4*)&B0[t0+t][i4*4];
                    accA[t] += h.x*wA[0]+h.y*wA[1]+h.z*wA[2]+h.w*wA[3];
                    accB[t] += h.x*wB[0]+h.y*wB[1]+h.z*wB[2]+h.w*wB[3];
                }
            }
        };
        float aA[8], aB[8];
        proj(Wq, aA, aB);
        #pragma unroll
        for (int t = 0; t < 8; t++){ B1[t0+t][j0]=aA[t]; B1[t0+t][j0+64]=aB[t]; }
        proj(Wk, aA, aB);
        #pragma unroll
        for (int t = 0; t < 8; t++){ B2[t0+t][j0]=aA[t]; B2[t0+t][j0+64]=aB[t]; }
        proj(Wv, aA, aB);
        #pragma unroll
        for (int t = 0; t < 8; t++){
            float r = radn[(size_t)n*32 + t0 + t];   // fold cutoff mask into V rows
            B0[t0+t][j0]=aA[t]*r; B0[t0+t][j0+64]=aB[t]*r;
        }
    }
    __syncthreads();

    {   // scores: wave = head; k preloaded to regs, then sc overwrites B2
        const int h = wv, s = lane >> 1, tt0 = (lane & 1)*16;
        float kreg[32];
        #pragma unroll
        for (int i4 = 0; i4 < 8; i4++){
            float4 k4 = *(const float4*)&B2[s][h*32+i4*4];
            kreg[i4*4+0]=k4.x; kreg[i4*4+1]=k4.y; kreg[i4*4+2]=k4.z; kreg[i4*4+3]=k4.w;
        }
        __syncthreads();   // all k reads complete before sc overwrites B2
        float acc[16];
        #pragma unroll
        for (int t = 0; t < 16; t++) acc[t] = 0.f;
        #pragma unroll
        for (int i4 = 0; i4 < 8; i4++){
            #pragma unroll
            for (int t = 0; t < 16; t++){
                float4 q4 = *(const float4*)&B1[tt0+t][h*32+i4*4];
                acc[t] += q4.x*kreg[i4*4+0]+q4.y*kreg[i4*4+1]+q4.z*kreg[i4*4+2]+q4.w*kreg[i4*4+3];
            }
        }
        float* sc = &B2[0][0];   // [4][32][33]
        #pragma unroll
        for (int t = 0; t < 16; t++) sc[h*1056 + (tt0+t)*33 + s] = acc[t]*0.17677669529663689f;
    }
    __syncthreads();

    if (tid < 128){   // softmax over all 32 slots (mask already folded into V)
        int h = tid >> 5, t = tid & 31;
        const float* sc = &B2[0][0];
        float* p = &B1[0][0];   // [4][32][32], slot-swizzled
        float buf[32], m = -1e30f;
        #pragma unroll
        for (int sp = 0; sp < 8; sp++){   // read in swizzled (physical) order: static reg idx
            int sl = (sp ^ (t & 7)) * 4;
            #pragma unroll
            for (int w = 0; w < 4; w++){
                float v = sc[h*1056 + t*33 + sl + w];
                buf[sp*4+w] = v; m = fmaxf(m, v);
            }
        }
        float sum = 0;
        #pragma unroll
        for (int i = 0; i < 32; i++){ buf[i] = __expf(buf[i]-m); sum += buf[i]; }
        float inv = 1.f/sum;
        #pragma unroll
        for (int sp = 0; sp < 8; sp++){
            float4 w4 = { buf[sp*4+0]*inv, buf[sp*4+1]*inv, buf[sp*4+2]*inv, buf[sp*4+3]*inv };
            *(float4*)&p[h*1024 + t*32 + sp*4] = w4;   // physical slot sp holds logical block sp^(t&7)
        }
    }
    __syncthreads();

    {   // PV: out[t][j] = sum_s p[h(j)][t][s] * v[s][j] -> B2 (own rows)
        const int h0 = j0 >> 5, h1 = h0 + 2;
        const float* p = &B1[0][0];
        float acc0[8], acc1[8];
        #pragma unroll
        for (int t = 0; t < 8; t++){ acc0[t]=0.f; acc1[t]=0.f; }
        #pragma unroll
        for (int s4 = 0; s4 < 8; s4++){
            float v0[4], v1[4];
            #pragma unroll
            for (int d2 = 0; d2 < 4; d2++){ v0[d2]=B0[s4*4+d2][j0]; v1[d2]=B0[s4*4+d2][j0+64]; }
            #pragma unroll
            for (int t = 0; t < 8; t++){
                int row = t0+t;
                int sp = (s4 ^ (row & 7)) << 2;   // physical slot of logical block s4
                float4 p0 = *(const float4*)&p[h0*1024 + row*32 + sp];
                float4 p1 = *(const float4*)&p[h1*1024 + row*32 + sp];
                acc0[t] += p0.x*v0[0]+p0.y*v0[1]+p0.z*v0[2]+p0.w*v0[3];
                acc1[t] += p1.x*v1[0]+p1.y*v1[1]+p1.z*v1[2]+p1.w*v1[3];
            }
        }
        #pragma unroll
        for (int t = 0; t < 8; t++){ B2[t0+t][j0]=acc0[t]; B2[t0+t][j0+64]=acc1[t]; }
    }
    // no barrier: O-proj reads only this wave's own B2 rows

    {   // O-projection + residual (from regs) + store
        float accA[8], accB[8];
        #pragma unroll
        for (int t = 0; t < 8; t++){ accA[t]=0.f; accB[t]=0.f; }
        for (int i4 = 0; i4 < 32; i4++){
            float wA[4], wB[4];
            #pragma unroll
            for (int d2 = 0; d2 < 4; d2++){
                wA[d2] = Wo[(i4*4+d2)*D + j0];
                wB[d2] = Wo[(i4*4+d2)*D + j0+64];
            }
            #pragma unroll
            for (int t = 0; t < 8; t++){
                float4 h = *(const float4*)&B2[t0+t][i4*4];
                accA[t] += h.x*wA[0]+h.y*wA[1]+h.z*wA[2]+h.w*wA[3];
                accB[t] += h.x*wB[0]+h.y*wB[1]+h.z*wB[2]+h.w*wB[3];
            }
        }
        #pragma unroll
        for (int t = 0; t < 8; t++){
            Xn[(t0+t)*D + j0]    = resA[t] + accA[t];
            Xn[(t0+t)*D + j0+64] = resB[t] + accB[t];
        }
    }
}

// Fused FFN block: x += gelu(LN(x)@W1 + b1)@W2 + b2   (16 tokens per block, 49920 B LDS)
__global__ __launch_bounds__(256) void k_ffn(float* __restrict__ X,
        const float* __restrict__ W1, const float* __restrict__ b1,
        const float* __restrict__ W2, const float* __restrict__ b2,
        const float* __restrict__ lnw, const float* __restrict__ lnb){
    __shared__ float xs[16][132];
    __shared__ float hh[16][132];
    __shared__ float mid[16][516];
    int tid = threadIdx.x, lane = tid & 63, wv = tid >> 6;
    float* Xg = X + (size_t)blockIdx.x * 16 * D;
    for (int idx = tid; idx < 16*32; idx += 256){
        int r = idx >> 5, c4 = idx & 31;
        *(float4*)&xs[r][c4*4] = ((const float4*)Xg)[idx];
    }
    __syncthreads();
    {   // LN: 16 threads per row
        int row = tid >> 4, l16 = tid & 15;
        float s = 0, ss = 0;
        #pragma unroll
        for (int k = 0; k < 8; k++){ float v = xs[row][l16+16*k]; s += v; ss += v*v; }
        #pragma unroll
        for (int m = 1; m < 16; m <<= 1){ s += __shfl_xor(s, m); ss += __shfl_xor(ss, m); }
        float mean = s*(1.f/128.f);
        float rstd = rsqrtf(ss*(1.f/128.f) - mean*mean + 1e-5f);
        #pragma unroll
        for (int k = 0; k < 8; k++){
            int j = l16+16*k;
            hh[row][j] = (xs[row][j]-mean)*rstd*lnw[j] + lnb[j];
        }
    }
    __syncthreads();
    {   // FFN1 + gelu: wave owns 128-wide j slice of the 512, all 16 tokens in regs
        int jA = wv*128 + lane, jB = jA + 64;
        float accA[16], accB[16];
        #pragma unroll
        for (int t = 0; t < 16; t++){ accA[t]=0.f; accB[t]=0.f; }
        for (int i4 = 0; i4 < 32; i4++){
            float wA[4], wB[4];
            #pragma unroll
            for (int d2 = 0; d2 < 4; d2++){
                wA[d2] = W1[(i4*4+d2)*FF + jA];
                wB[d2] = W1[(i4*4+d2)*FF + jB];
            }
            #pragma unroll
            for (int t = 0; t < 16; t++){
                float4 h = *(const float4*)&hh[t][i4*4];
                accA[t] += h.x*wA[0]+h.y*wA[1]+h.z*wA[2]+h.w*wA[3];
                accB[t] += h.x*wB[0]+h.y*wB[1]+h.z*wB[2]+h.w*wB[3];
            }
        }
        float biasA = b1[jA], biasB = b1[jB];
        #pragma unroll
        for (int t = 0; t < 16; t++){
            mid[t][jA] = gelu_f(accA[t]+biasA);
            mid[t][jB] = gelu_f(accB[t]+biasB);
        }
    }
    __syncthreads();
    {   // FFN2 + bias + residual
        int j = wv*32 + (lane & 31), t0 = (lane >> 5)*8;
        float acc[8];
        #pragma unroll
        for (int t = 0; t < 8; t++) acc[t] = 0.f;
        for (int i4 = 0; i4 < 128; i4++){
            float w[4];
            #pragma unroll
            for (int d2 = 0; d2 < 4; d2++) w[d2] = W2[(i4*4+d2)*D + j];
            #pragma unroll
            for (int t = 0; t < 8; t++){
                float4 m4 = *(const float4*)&mid[t0+t][i4*4];
                acc[t] += m4.x*w[0]+m4.y*w[1]+m4.z*w[2]+m4.w*w[3];
            }
        }
        float bias = b2[j];
        #pragma unroll
        for (int t = 0; t < 8; t++) Xg[(t0+t)*D + j] = xs[t0+t][j] + acc[t] + bias;
    }
}

// Edge contraction: Y_edge = [feats_edge(e), feats_edge(corr[e])] @ g_contr, nef layout out
__global__ __launch_bounds__(256) void k_contract(const float* __restrict__ X,
        const int* __restrict__ centers, const int* __restrict__ CORR,
        const float* __restrict__ gc, float* __restrict__ Y){
    __shared__ float ab[16][260];
    int tid = threadIdx.x, lane = tid & 63, wv = tid >> 6;
    int e0 = blockIdx.x * 16;
    for (int idx = tid; idx < 16*32; idx += 256){
        int r = idx >> 5, c4 = idx & 31;
        int e = e0 + r;
        int cS = centers[e];
        int rowS = cS*32 + (e - cS*K_NB);
        *(float4*)&ab[r][c4*4] = *(const float4*)&X[(size_t)rowS*D + c4*4];
        int ec = CORR[e];
        int cC = centers[ec];
        int rowC = cC*32 + (ec - cC*K_NB);
        *(float4*)&ab[r][128 + c4*4] = *(const float4*)&X[(size_t)rowC*D + c4*4];
    }
    __syncthreads();
    int j = wv*32 + (lane & 31), t0 = (lane >> 5)*8;
    float acc[8];
    #pragma unroll
    for (int t = 0; t < 8; t++) acc[t] = 0.f;
    for (int i4 = 0; i4 < 64; i4++){
        float w[4];
        #pragma unroll
        for (int d2 = 0; d2 < 4; d2++) w[d2] = gc[(i4*4+d2)*D + j];
        #pragma unroll
        for (int t = 0; t < 8; t++){
            float4 a4 = *(const float4*)&ab[t0+t][i4*4];
            acc[t] += a4.x*w[0]+a4.y*w[1]+a4.z*w[2]+a4.w*w[3];
        }
    }
    #pragma unroll
    for (int t = 0; t < 8; t++){
        int e = e0 + t0 + t;
        int cS = centers[e];
        Y[((size_t)cS*32 + (e - cS*K_NB))*D + j] = acc[t];
    }
}

__global__ void k_padfill(float* __restrict__ Y){
    int idx = blockIdx.x*256 + threadIdx.x;
    if (idx >= N_NODES*8*D) return;
    int j = idx & 127, rs = idx >> 7;
    int n = rs >> 3, sr = rs & 7;
    Y[((size_t)n*32 + K_NB + sr)*D + j] = Y[j];   // contracted value of edge 0 (nef_idx=0)
}

__global__ __launch_bounds__(256) void k_readout(const float* __restrict__ X,
        const float* __restrict__ Y, const float* __restrict__ rW,
        const float* __restrict__ radn, const int* __restrict__ ELEM,
        const float* __restrict__ cw, float* __restrict__ out){
    __shared__ float rws[128];
    __shared__ float wsum[4];
    int S = blockIdx.x, tid = threadIdx.x, lane = tid & 63, wv = tid >> 6;
    if (tid < 128) rws[tid] = rW[tid];
    __syncthreads();
    float acc = 0.f;
    for (int r = wv; r < PER*32; r += 4){
        size_t row = (size_t)S*PER*32 + r;
        float rad = radn[row];
        if (rad != 0.f){
            const float* xr = X + row*D;
            const float* yr = Y + row*D;
            acc += rad * ((xr[lane]+yr[lane])*rws[lane] + (xr[lane+64]+yr[lane+64])*rws[lane+64]);
        }
    }
    for (int nl = tid; nl < PER; nl += 256) acc += cw[ELEM[S*PER + nl]];
    #pragma unroll
    for (int m = 1; m < 64; m <<= 1) acc += __shfl_xor(acc, m);
    if (lane == 0) wsum[wv] = acc;
    __syncthreads();
    if (tid == 0) out[S] = wsum[0]+wsum[1]+wsum[2]+wsum[3];
}

extern "C" void kernel_launch(void* const* d_in, const int* in_sizes, int n_in,
                              void* d_out, int out_size, void* d_ws, size_t ws_size,
                              hipStream_t stream){
    const float* positions   = (const float*)d_in[0];
    const float* cells       = (const float*)d_in[1];
    const float* cell_shifts = (const float*)d_in[2];
    const float* enc_Wcart   = (const float*)d_in[3];
    const float* enc_emb_c   = (const float*)d_in[4];
    const float* enc_emb_n   = (const float*)d_in[5];
    const float* enc_Wcomp   = (const float*)d_in[6];
    const float* t_Wq  = (const float*)d_in[7];
    const float* t_Wk  = (const float*)d_in[8];
    const float* t_Wv  = (const float*)d_in[9];
    const float* t_Wo  = (const float*)d_in[10];
    const float* t_ln1w = (const float*)d_in[11];
    const float* t_ln1b = (const float*)d_in[12];
    const float* t_ln2w = (const float*)d_in[13];
    const float* t_ln2b = (const float*)d_in[14];
    const float* t_W1  = (const float*)d_in[15];
    const float* t_b1  = (const float*)d_in[16];
    const float* t_W2  = (const float*)d_in[17];
    const float* t_b2  = (const float*)d_in[18];
    const float* g_contr = (const float*)d_in[19];
    const float* g_Wq  = (const float*)d_in[20];
    const float* g_Wk  = (const float*)d_in[21];
    const float* g_Wv  = (const float*)d_in[22];
    const float* g_Wo  = (const float*)d_in[23];
    const float* g_ln1w = (const float*)d_in[24];
    const float* g_ln1b = (const float*)d_in[25];
    const float* g_ln2w = (const float*)d_in[26];
    const float* g_ln2b = (const float*)d_in[27];
    const float* g_W1  = (const float*)d_in[28];
    const float* g_b1  = (const float*)d_in[29];
    const float* g_W2  = (const float*)d_in[30];
    const float* g_b2  = (const float*)d_in[31];
    const float* readout_W = (const float*)d_in[32];
    const float* comp_w    = (const float*)d_in[33];
    const int* numbers   = (const int*)d_in[34];
    const int* centers   = (const int*)d_in[35];
    const int* neighbors = (const int*)d_in[36];

    float* ws = (float*)d_ws;
    float* X    = ws;                       // NTOK*D
    float* Y    = X + (size_t)NTOK*D;       // NTOK*D
    float* EV   = Y + (size_t)NTOK*D;       // N_EDGES*3
    float* RAD  = EV + (size_t)N_EDGES*3;   // N_EDGES
    float* RADN = RAD + N_EDGES;            // NTOK
    float* W3   = RADN + NTOK;              // 3*128
    float* ECn  = W3 + 3*128;               // 4*128
    float* ENn  = ECn + 4*128;              // 4*128
    int*   ELEM = (int*)(ENn + 4*128);      // N_NODES
    int*   CORR = ELEM + N_NODES;           // N_EDGES

    k_elem<<<(N_NODES+255)/256, 256, 0, stream>>>(numbers, ELEM);
    k_prep<<<1, 128, 0, stream>>>(enc_Wcart, enc_emb_c, enc_emb_n, enc_Wcomp, W3, ECn, ENn);
    k_edge<<<(N_EDGES+255)/256, 256, 0, stream>>>(positions, cells, cell_shifts, centers, neighbors, EV, RAD, CORR);
    k_encode<<<NTOK, 128, 0, stream>>>(EV, RAD, centers, neighbors, ELEM, W3, ECn, ENn, X, RADN);

    for (int l = 0; l < 2; l++){
        k_attn<<<N_NODES, 256, 0, stream>>>(X, t_Wq + l*16384, t_Wk + l*16384, t_Wv + l*16384,
                                            t_Wo + l*16384, t_ln1w + l*128, t_ln1b + l*128, RADN);
        k_ffn<<<NTOK/16, 256, 0, stream>>>(X, t_W1 + l*65536, t_b1 + l*512,
                                           t_W2 + l*65536, t_b2 + l*128,
                                           t_ln2w + l*128, t_ln2b + l*128);
    }

    k_contract<<<N_EDGES/16, 256, 0, stream>>>(X, centers, CORR, g_contr, Y);
    k_padfill<<<(N_NODES*8*D+255)/256, 256, 0, stream>>>(Y);

    for (int l = 0; l < 2; l++){
        k_attn<<<N_NODES, 256, 0, stream>>>(Y, g_Wq + l*16384, g_Wk + l*16384, g_Wv + l*16384,
                                            g_Wo + l*16384, g_ln1w + l*128, g_ln1b + l*128, RADN);
        k_ffn<<<NTOK/16, 256, 0, stream>>>(Y, g_W1 + l*65536, g_b1 + l*512,
                                           g_W2 + l*65536, g_b2 + l*128,
                                           g_ln2w + l*128, g_ln2b + l*128);
    }

    k_readout<<<N_STRUCT, 256, 0, stream>>>(X, Y, readout_W, RADN, ELEM, comp_w, (float*)d_out);
}

// Round 3
// 1532.766 us; speedup vs baseline: 4.0133x; 4.0133x over previous
//
#include <hip/hip_runtime.h>
#include <hip/hip_bf16.h>
#include <math.h>

#define N_NODES 5000
#define N_STRUCT 50
#define PER 100
#define K_NB 24
#define N_EDGES (N_NODES*K_NB)
#define TMAX 32
#define D 128
#define FF 512
#define NTOK (N_NODES*TMAX)

typedef short bf16x8 __attribute__((ext_vector_type(8)));
typedef float f32x4  __attribute__((ext_vector_type(4)));
#define MFMA_B16(a,b,c) __builtin_amdgcn_mfma_f32_16x16x32_bf16(a,b,c,0,0,0)

__device__ __forceinline__ short f2bf(float x){           // RTNE float->bf16 bits
    unsigned u = __float_as_uint(x);
    return (short)((u + 0x7FFFu + ((u>>16)&1u)) >> 16);
}

__device__ __forceinline__ float gelu_f(float x){         // tanh-approx gelu, overflow-safe
    float E = __expf(1.5957691216057308f*(x + 0.044715f*x*x*x));  // e^{2u}
    return x - x/(E+1.f);                                  // = 0.5x(1+tanh(u))
}

__device__ __forceinline__ float cutoff_f(float r){
    if (r < 3.f) return 1.f;
    if (r >= 5.f) return 0.f;
    float x = (r-3.f)*0.5f;
    return 0.5f*(1.f + cosf(3.14159265358979323846f * x));
}

__global__ void k_zero(float* out){
    for (int i = threadIdx.x; i < N_STRUCT; i += 64) out[i] = 0.f;
}

__global__ void k_elem(const int* __restrict__ numbers, int* __restrict__ ELEM){
    int i = blockIdx.x*256 + threadIdx.x;
    if (i < N_NODES){
        int z = numbers[i];
        ELEM[i] = (z==1)?0:(z==6)?1:(z==7)?2:(z==8)?3:-1;
    }
}

__global__ void k_prep(const float* __restrict__ Wcart, const float* __restrict__ embc,
                       const float* __restrict__ embn, const float* __restrict__ Wcomp,
                       float* __restrict__ W3, float* __restrict__ ECn, float* __restrict__ ENn){
    int j = threadIdx.x; // 128
    for (int a = 0; a < 3; a++){
        float s = 0;
        for (int i = 0; i < 128; i++) s += Wcart[a*128+i]*Wcomp[i*128+j];
        W3[a*128+j] = s;
    }
    for (int sp = 0; sp < 4; sp++){
        float s1 = 0, s2 = 0;
        for (int i = 0; i < 128; i++){
            s1 += embc[sp*128+i]*Wcomp[(128+i)*128+j];
            s2 += embn[sp*128+i]*Wcomp[(256+i)*128+j];
        }
        ECn[sp*128+j] = s1; ENn[sp*128+j] = s2;
    }
}

// transpose+bf16-convert all GEMM weights into WT (dst layout [out][in], k-contiguous)
__global__ void k_wt(const float* tWq, const float* tWk, const float* tWv, const float* tWo,
                     const float* tW1, const float* tW2, const float* gWq, const float* gWk,
                     const float* gWv, const float* gWo, const float* gW1, const float* gW2,
                     const float* gct, short* __restrict__ WT){
    const int  sel[25]  = {0,0,1,1,2,2,3,3,4,4,5,5,6,6,7,7,8,8,9,9,10,10,11,11,12};
    const int  lin[25]  = {7,7,7,7,7,7,7,7,7,7,9,9,7,7,7,7,7,7,7,7,7,7,9,9,8};
    const int  lout[25] = {7,7,7,7,7,7,7,7,9,9,7,7,7,7,7,7,7,7,7,7,9,9,7,7,7};
    const int  soff[25] = {0,16384,0,16384,0,16384,0,16384,0,65536,0,65536,
                           0,16384,0,16384,0,16384,0,16384,0,65536,0,65536,0};
    const int  doff[25] = {0,16384,32768,49152,65536,81920,98304,114688,
                           131072,196608,262144,327680,
                           393216,409600,425984,442368,458752,475136,491520,507904,
                           524288,589824,655360,720896,786432};
    int gid = blockIdx.x*256 + threadIdx.x;
    if (gid >= 819200) return;
    int r = 0, base = 0;
    while (true){
        int sz = 1 << (lin[r]+lout[r]);
        if (gid < base + sz) break;
        base += sz; r++;
    }
    int d = gid - base;
    int j = d >> lin[r], i = d & ((1<<lin[r])-1);
    const float* src;
    switch (sel[r]){
        case 0: src=tWq; break; case 1: src=tWk; break; case 2: src=tWv; break; case 3: src=tWo; break;
        case 4: src=tW1; break; case 5: src=tW2; break;
        case 6: src=gWq; break; case 7: src=gWk; break; case 8: src=gWv; break; case 9: src=gWo; break;
        case 10: src=gW1; break; case 11: src=gW2; break; default: src=gct; break;
    }
    WT[doff[r] + d] = f2bf(src[soff[r] + (i<<lout[r]) + j]);
}

__global__ void k_edge(const float* __restrict__ pos, const float* __restrict__ cells,
                       const float* __restrict__ shifts, const int* __restrict__ centers,
                       const int* __restrict__ neighbors, float* __restrict__ EV,
                       float* __restrict__ RAD, int* __restrict__ CORR){
    int e = blockIdx.x*256 + threadIdx.x;
    if (e >= N_EDGES) return;
    int c = centers[e], nb = neighbors[e];
    int st = c / PER;
    const float* cell = cells + st*9;
    float s0 = shifts[e*3+0], s1 = shifts[e*3+1], s2 = shifts[e*3+2];
    float ex = pos[nb*3+0]-pos[c*3+0] + s0*cell[0]+s1*cell[3]+s2*cell[6];
    float ey = pos[nb*3+1]-pos[c*3+1] + s0*cell[1]+s1*cell[4]+s2*cell[7];
    float ez = pos[nb*3+2]-pos[c*3+2] + s0*cell[2]+s1*cell[5]+s2*cell[8];
    EV[e*3+0] = ex; EV[e*3+1] = ey; EV[e*3+2] = ez;
    RAD[e] = cutoff_f(sqrtf(ex*ex+ey*ey+ez*ez));
    int base = nb*K_NB, corr = base;
    for (int k2 = 0; k2 < K_NB; k2++){
        if (neighbors[base+k2] == c){ corr = base+k2; break; }
    }
    CORR[e] = corr;
}

__global__ void k_encode(const float* __restrict__ EV, const float* __restrict__ RAD,
                         const int* __restrict__ centers, const int* __restrict__ neighbors,
                         const int* __restrict__ ELEM, const float* __restrict__ W3,
                         const float* __restrict__ ECn, const float* __restrict__ ENn,
                         float* __restrict__ X, float* __restrict__ RADN){
    int row = blockIdx.x;   // 0..NTOK-1
    int j = threadIdx.x;    // 0..127
    int n = row >> 5, s = row & 31;
    int e = (s < K_NB) ? (n*K_NB + s) : 0;   // padding slots replicate edge 0 (nef_idx=0)
    int ec = ELEM[centers[e]], en = ELEM[neighbors[e]];
    float ev0 = EV[e*3+0], ev1 = EV[e*3+1], ev2 = EV[e*3+2];
    float v = ev0*W3[j] + ev1*W3[128+j] + ev2*W3[256+j] + ECn[ec*128+j] + ENn[en*128+j];
    X[(size_t)row*D + j] = v;
    if (j == 0) RADN[row] = (s < K_NB) ? RAD[e] : 0.f;
}

// ---------------- MFMA attention: one node (32 tokens) per block ----------------
// Frag layouts (m89/m120-verified): A[m=lane&15][k=quad*8+j]; B[k=quad*8+j][n=lane&15];
// C/D col=lane&15, row=quad*4+reg.
__global__ __launch_bounds__(256) void k_attn_mfma(float* __restrict__ X,
        const short* __restrict__ Wqt, const short* __restrict__ Wkt,
        const short* __restrict__ Wvt, const short* __restrict__ Wot,
        const float* __restrict__ lnw, const float* __restrict__ lnb,
        const float* __restrict__ radn){
    __shared__ short hh[32*136];    // LN out, [t][j]
    __shared__ short Qs[32*136];    // Q[t][j] (scaled); aliased as OB[t][j] after scores
    __shared__ short Ks[32*136];    // K[s][j]
    __shared__ short VT[128*40];    // V^T[j][s], mask folded
    __shared__ short Ps[4*32*40];   // P[h][t][s]
    __shared__ float radl[32];
    const int n = blockIdx.x, tid = threadIdx.x, lane = tid & 63, w = tid >> 6;
    const int quad = lane >> 4, l16 = lane & 15;
    float* Xn = X + (size_t)n*32*128;
    if (tid < 32) radl[tid] = radn[(size_t)n*32 + tid];
    {   // LayerNorm from global, 8 threads/row -> hh bf16
        int row = tid >> 3, l8 = tid & 7;
        f32x4 v[4];
        #pragma unroll
        for (int c = 0; c < 4; c++) v[c] = *(const f32x4*)&Xn[row*128 + l8*16 + c*4];
        float s = 0, ss = 0;
        #pragma unroll
        for (int c = 0; c < 4; c++){
            #pragma unroll
            for (int k = 0; k < 4; k++){ s += v[c][k]; ss += v[c][k]*v[c][k]; }
        }
        #pragma unroll
        for (int m = 1; m < 8; m <<= 1){ s += __shfl_xor(s, m); ss += __shfl_xor(ss, m); }
        float mean = s*(1.f/128.f);
        float rstd = rsqrtf(ss*(1.f/128.f) - mean*mean + 1e-5f);
        #pragma unroll
        for (int c = 0; c < 4; c++){
            f32x4 wv4 = *(const f32x4*)&lnw[l8*16 + c*4];
            f32x4 bv4 = *(const f32x4*)&lnb[l8*16 + c*4];
            short4 pk;
            pk.x = f2bf((v[c][0]-mean)*rstd*wv4[0] + bv4[0]);
            pk.y = f2bf((v[c][1]-mean)*rstd*wv4[1] + bv4[1]);
            pk.z = f2bf((v[c][2]-mean)*rstd*wv4[2] + bv4[2]);
            pk.w = f2bf((v[c][3]-mean)*rstd*wv4[3] + bv4[3]);
            *(short4*)&hh[row*136 + l8*16 + c*4] = pk;
        }
    }
    __syncthreads();
    {   // QKV. Q^T,K^T: D[m=j][n=t], wave m-range [w*32,+32). V: D[m=s][n=j], wave n-range.
        f32x4 z = {0.f,0.f,0.f,0.f};
        f32x4 qacc[4], kacc[4], vacc[4];
        #pragma unroll
        for (int i = 0; i < 4; i++){ qacc[i]=z; kacc[i]=z; vacc[i]=z; }
        #pragma unroll
        for (int kk = 0; kk < 4; kk++){
            bf16x8 h0 = *(const bf16x8*)&hh[(l16)*136    + kk*32 + quad*8];
            bf16x8 h1 = *(const bf16x8*)&hh[(16+l16)*136 + kk*32 + quad*8];
            #pragma unroll
            for (int mt = 0; mt < 2; mt++){
                bf16x8 aq = *(const bf16x8*)&Wqt[(w*32+mt*16+l16)*128 + kk*32 + quad*8];
                bf16x8 ak = *(const bf16x8*)&Wkt[(w*32+mt*16+l16)*128 + kk*32 + quad*8];
                bf16x8 bv = *(const bf16x8*)&Wvt[(w*32+mt*16+l16)*128 + kk*32 + quad*8];
                qacc[mt*2+0] = MFMA_B16(aq, h0, qacc[mt*2+0]);
                qacc[mt*2+1] = MFMA_B16(aq, h1, qacc[mt*2+1]);
                kacc[mt*2+0] = MFMA_B16(ak, h0, kacc[mt*2+0]);
                kacc[mt*2+1] = MFMA_B16(ak, h1, kacc[mt*2+1]);
                vacc[0*2+mt] = MFMA_B16(h0, bv, vacc[0*2+mt]);   // mt is nt for V
                vacc[1*2+mt] = MFMA_B16(h1, bv, vacc[1*2+mt]);
            }
        }
        #pragma unroll
        for (int mt = 0; mt < 2; mt++){
            #pragma unroll
            for (int nt = 0; nt < 2; nt++){
                {   // Q^T tile: col t, rows j -> Qs[t][j] packed (scale folded)
                    int t = nt*16 + l16, jb = w*32 + mt*16 + quad*4;
                    short4 pk;
                    pk.x = f2bf(qacc[mt*2+nt][0]*0.17677669529663689f);
                    pk.y = f2bf(qacc[mt*2+nt][1]*0.17677669529663689f);
                    pk.z = f2bf(qacc[mt*2+nt][2]*0.17677669529663689f);
                    pk.w = f2bf(qacc[mt*2+nt][3]*0.17677669529663689f);
                    *(short4*)&Qs[t*136 + jb] = pk;
                    short4 pk2;
                    pk2.x = f2bf(kacc[mt*2+nt][0]); pk2.y = f2bf(kacc[mt*2+nt][1]);
                    pk2.z = f2bf(kacc[mt*2+nt][2]); pk2.w = f2bf(kacc[mt*2+nt][3]);
                    *(short4*)&Ks[t*136 + jb] = pk2;
                }
                {   // V tile: col j, rows s -> VT[j][s] packed, *rad[s]
                    int j = w*32 + nt*16 + l16, sb = mt*16 + quad*4;
                    f32x4 r4 = *(const f32x4*)&radl[sb];
                    short4 pk;
                    pk.x = f2bf(vacc[mt*2+nt][0]*r4[0]); pk.y = f2bf(vacc[mt*2+nt][1]*r4[1]);
                    pk.z = f2bf(vacc[mt*2+nt][2]*r4[2]); pk.w = f2bf(vacc[mt*2+nt][3]*r4[3]);
                    *(short4*)&VT[j*40 + sb] = pk;
                }
            }
        }
    }
    __syncthreads();
    {   // scores + softmax + P write; wave = head
        const int h = w;
        bf16x8 qa0 = *(const bf16x8*)&Qs[(l16)*136    + h*32 + quad*8];
        bf16x8 qa1 = *(const bf16x8*)&Qs[(16+l16)*136 + h*32 + quad*8];
        bf16x8 kb0 = *(const bf16x8*)&Ks[(l16)*136    + h*32 + quad*8];
        bf16x8 kb1 = *(const bf16x8*)&Ks[(16+l16)*136 + h*32 + quad*8];
        f32x4 z = {0.f,0.f,0.f,0.f};
        f32x4 sc00 = MFMA_B16(qa0, kb0, z), sc01 = MFMA_B16(qa0, kb1, z);
        f32x4 sc10 = MFMA_B16(qa1, kb0, z), sc11 = MFMA_B16(qa1, kb1, z);
        #pragma unroll
        for (int mt = 0; mt < 2; mt++){
            f32x4 s0 = mt ? sc10 : sc00, s1 = mt ? sc11 : sc01;
            #pragma unroll
            for (int r = 0; r < 4; r++){
                float mx = fmaxf(s0[r], s1[r]);
                #pragma unroll
                for (int dlt = 1; dlt < 16; dlt <<= 1) mx = fmaxf(mx, __shfl_xor(mx, dlt));
                float e0 = __expf(s0[r]-mx), e1 = __expf(s1[r]-mx);
                float sm = e0 + e1;
                #pragma unroll
                for (int dlt = 1; dlt < 16; dlt <<= 1) sm += __shfl_xor(sm, dlt);
                float inv = 1.f/sm;
                int t = mt*16 + quad*4 + r;
                Ps[h*1280 + t*40 + l16]      = f2bf(e0*inv);
                Ps[h*1280 + t*40 + 16 + l16] = f2bf(e1*inv);
            }
        }
    }
    __syncthreads();   // Q reads done: Qs reusable as OB
    short* OB = Qs;
    {   // PV: wave = head; D[m=t][n=j within head]
        const int h = w;
        bf16x8 pa0 = *(const bf16x8*)&Ps[h*1280 + (l16)*40    + quad*8];
        bf16x8 pa1 = *(const bf16x8*)&Ps[h*1280 + (16+l16)*40 + quad*8];
        bf16x8 vb0 = *(const bf16x8*)&VT[(h*32 + l16)*40      + quad*8];
        bf16x8 vb1 = *(const bf16x8*)&VT[(h*32 + 16 + l16)*40 + quad*8];
        f32x4 z = {0.f,0.f,0.f,0.f};
        f32x4 o00 = MFMA_B16(pa0, vb0, z), o01 = MFMA_B16(pa0, vb1, z);
        f32x4 o10 = MFMA_B16(pa1, vb0, z), o11 = MFMA_B16(pa1, vb1, z);
        #pragma unroll
        for (int mt = 0; mt < 2; mt++){
            #pragma unroll
            for (int nt = 0; nt < 2; nt++){
                f32x4 ov = mt ? (nt ? o11 : o10) : (nt ? o01 : o00);
                int j = h*32 + nt*16 + l16;
                #pragma unroll
                for (int r = 0; r < 4; r++){
                    int t = mt*16 + quad*4 + r;
                    OB[t*136 + j] = f2bf(ov[r]);
                }
            }
        }
    }
    __syncthreads();
    {   // O-projection + residual; wave n-range [w*32,+32)
        f32x4 z = {0.f,0.f,0.f,0.f};
        f32x4 oc[4] = {z,z,z,z};
        #pragma unroll
        for (int kk = 0; kk < 4; kk++){
            bf16x8 a0 = *(const bf16x8*)&OB[(l16)*136    + kk*32 + quad*8];
            bf16x8 a1 = *(const bf16x8*)&OB[(16+l16)*136 + kk*32 + quad*8];
            #pragma unroll
            for (int nt = 0; nt < 2; nt++){
                bf16x8 bo = *(const bf16x8*)&Wot[(w*32+nt*16+l16)*128 + kk*32 + quad*8];
                oc[0+nt] = MFMA_B16(a0, bo, oc[0+nt]);
                oc[2+nt] = MFMA_B16(a1, bo, oc[2+nt]);
            }
        }
        #pragma unroll
        for (int mt = 0; mt < 2; mt++){
            #pragma unroll
            for (int nt = 0; nt < 2; nt++){
                int j2 = w*32 + nt*16 + l16;
                #pragma unroll
                for (int r = 0; r < 4; r++){
                    int t = mt*16 + quad*4 + r;
                    Xn[t*128 + j2] += oc[mt*2+nt][r];
                }
            }
        }
    }
}

// ---------------- MFMA FFN: 32 tokens per block ----------------
__global__ __launch_bounds__(256) void k_ffn_mfma(float* __restrict__ X,
        const short* __restrict__ W1t, const short* __restrict__ W2t,
        const float* __restrict__ b1, const float* __restrict__ b2,
        const float* __restrict__ lnw, const float* __restrict__ lnb){
    __shared__ short hh[32*136];     // LN out [t][i]
    __shared__ short mid[32*528];    // gelu out [t][ff]
    __shared__ float b1s[512];
    __shared__ float b2s[128];
    const int tid = threadIdx.x, lane = tid & 63, w = tid >> 6;
    const int quad = lane >> 4, l16 = lane & 15;
    float* Xg = X + (size_t)blockIdx.x*32*128;
    for (int i = tid; i < 512; i += 256) b1s[i] = b1[i];
    if (tid < 128) b2s[tid] = b2[tid];
    {   // LN
        int row = tid >> 3, l8 = tid & 7;
        f32x4 v[4];
        #pragma unroll
        for (int c = 0; c < 4; c++) v[c] = *(const f32x4*)&Xg[row*128 + l8*16 + c*4];
        float s = 0, ss = 0;
        #pragma unroll
        for (int c = 0; c < 4; c++){
            #pragma unroll
            for (int k = 0; k < 4; k++){ s += v[c][k]; ss += v[c][k]*v[c][k]; }
        }
        #pragma unroll
        for (int m = 1; m < 8; m <<= 1){ s += __shfl_xor(s, m); ss += __shfl_xor(ss, m); }
        float mean = s*(1.f/128.f);
        float rstd = rsqrtf(ss*(1.f/128.f) - mean*mean + 1e-5f);
        #pragma unroll
        for (int c = 0; c < 4; c++){
            f32x4 wv4 = *(const f32x4*)&lnw[l8*16 + c*4];
            f32x4 bv4 = *(const f32x4*)&lnb[l8*16 + c*4];
            short4 pk;
            pk.x = f2bf((v[c][0]-mean)*rstd*wv4[0] + bv4[0]);
            pk.y = f2bf((v[c][1]-mean)*rstd*wv4[1] + bv4[1]);
            pk.z = f2bf((v[c][2]-mean)*rstd*wv4[2] + bv4[2]);
            pk.w = f2bf((v[c][3]-mean)*rstd*wv4[3] + bv4[3]);
            *(short4*)&hh[row*136 + l8*16 + c*4] = pk;
        }
    }
    __syncthreads();
    {   // FFN1 transposed: D[m=ff][n=t]; wave m-range [w*128,+128)
        f32x4 z = {0.f,0.f,0.f,0.f};
        f32x4 acc[16];
        #pragma unroll
        for (int i = 0; i < 16; i++) acc[i] = z;
        #pragma unroll
        for (int kk = 0; kk < 4; kk++){
            bf16x8 h0 = *(const bf16x8*)&hh[(l16)*136    + kk*32 + quad*8];
            bf16x8 h1 = *(const bf16x8*)&hh[(16+l16)*136 + kk*32 + quad*8];
            #pragma unroll
            for (int mt = 0; mt < 8; mt++){
                bf16x8 a = *(const bf16x8*)&W1t[(size_t)(w*128+mt*16+l16)*128 + kk*32 + quad*8];
                acc[mt*2+0] = MFMA_B16(a, h0, acc[mt*2+0]);
                acc[mt*2+1] = MFMA_B16(a, h1, acc[mt*2+1]);
            }
        }
        #pragma unroll
        for (int mt = 0; mt < 8; mt++){
            int fb = w*128 + mt*16 + quad*4;
            f32x4 bb = *(const f32x4*)&b1s[fb];
            #pragma unroll
            for (int nt = 0; nt < 2; nt++){
                int t = nt*16 + l16;
                short4 pk;
                pk.x = f2bf(gelu_f(acc[mt*2+nt][0] + bb[0]));
                pk.y = f2bf(gelu_f(acc[mt*2+nt][1] + bb[1]));
                pk.z = f2bf(gelu_f(acc[mt*2+nt][2] + bb[2]));
                pk.w = f2bf(gelu_f(acc[mt*2+nt][3] + bb[3]));
                *(short4*)&mid[t*528 + fb] = pk;
            }
        }
    }
    __syncthreads();
    {   // FFN2: D[m=t][n=j]; wave n-range [w*32,+32)
        f32x4 z = {0.f,0.f,0.f,0.f};
        f32x4 o[4] = {z,z,z,z};
        #pragma unroll
        for (int kk = 0; kk < 16; kk++){
            bf16x8 a0 = *(const bf16x8*)&mid[(l16)*528    + kk*32 + quad*8];
            bf16x8 a1 = *(const bf16x8*)&mid[(16+l16)*528 + kk*32 + quad*8];
            #pragma unroll
            for (int nt = 0; nt < 2; nt++){
                bf16x8 bw = *(const bf16x8*)&W2t[(size_t)(w*32+nt*16+l16)*512 + kk*32 + quad*8];
                o[0+nt] = MFMA_B16(a0, bw, o[0+nt]);
                o[2+nt] = MFMA_B16(a1, bw, o[2+nt]);
            }
        }
        #pragma unroll
        for (int mt = 0; mt < 2; mt++){
            #pragma unroll
            for (int nt = 0; nt < 2; nt++){
                int j = w*32 + nt*16 + l16;
                #pragma unroll
                for (int r = 0; r < 4; r++){
                    int t = mt*16 + quad*4 + r;
                    Xg[t*128 + j] = Xg[t*128 + j] + o[mt*2+nt][r] + b2s[j];
                }
            }
        }
    }
}

// ---------------- MFMA edge contraction: 32 edges per block ----------------
__global__ __launch_bounds__(256) void k_contract_mfma(const float* __restrict__ X,
        const int* __restrict__ centers, const int* __restrict__ CORR,
        const short* __restrict__ gct, float* __restrict__ Y){
    __shared__ short ab[32*264];    // [edge][256 concat feats]
    const int tid = threadIdx.x, lane = tid & 63, w = tid >> 6;
    const int quad = lane >> 4, l16 = lane & 15;
    const int e0 = blockIdx.x*32;
    for (int idx = tid; idx < 2048; idx += 256){
        int r = idx >> 6, c4 = idx & 63;
        int e = e0 + r, srcRow;
        if (c4 < 32){ int c = centers[e]; srcRow = c*32 + (e - c*K_NB); }
        else        { int ec = CORR[e]; int c = centers[ec]; srcRow = c*32 + (ec - c*K_NB); }
        float4 v = *(const float4*)&X[(size_t)srcRow*128 + (c4 & 31)*4];
        short4 pk; pk.x = f2bf(v.x); pk.y = f2bf(v.y); pk.z = f2bf(v.z); pk.w = f2bf(v.w);
        *(short4*)&ab[r*264 + c4*4] = pk;
    }
    __syncthreads();
    f32x4 z = {0.f,0.f,0.f,0.f};
    f32x4 o[4] = {z,z,z,z};
    #pragma unroll
    for (int kk = 0; kk < 8; kk++){
        bf16x8 a0 = *(const bf16x8*)&ab[(l16)*264    + kk*32 + quad*8];
        bf16x8 a1 = *(const bf16x8*)&ab[(16+l16)*264 + kk*32 + quad*8];
        #pragma unroll
        for (int nt = 0; nt < 2; nt++){
            bf16x8 bw = *(const bf16x8*)&gct[(size_t)(w*32+nt*16+l16)*256 + kk*32 + quad*8];
            o[0+nt] = MFMA_B16(a0, bw, o[0+nt]);
            o[2+nt] = MFMA_B16(a1, bw, o[2+nt]);
        }
    }
    #pragma unroll
    for (int mt = 0; mt < 2; mt++){
        #pragma unroll
        for (int nt = 0; nt < 2; nt++){
            int j = w*32 + nt*16 + l16;
            #pragma unroll
            for (int r = 0; r < 4; r++){
                int e = e0 + mt*16 + quad*4 + r;
                int c = e / K_NB, slot = e - c*K_NB;
                Y[((size_t)c*32 + slot)*128 + j] = o[mt*2+nt][r];
            }
        }
    }
}

__global__ void k_padfill(float* __restrict__ Y){
    int idx = blockIdx.x*256 + threadIdx.x;
    if (idx >= N_NODES*8*D) return;
    int j = idx & 127, rs = idx >> 7;
    int n = rs >> 3, sr = rs & 7;
    Y[((size_t)n*32 + K_NB + sr)*D + j] = Y[j];   // contracted edge 0 (nef_idx=0)
}

__global__ __launch_bounds__(256) void k_readout(const float* __restrict__ X,
        const float* __restrict__ Y, const float* __restrict__ rW,
        const float* __restrict__ radn, const int* __restrict__ ELEM,
        const float* __restrict__ cw, float* __restrict__ out){
    __shared__ float rws[128];
    __shared__ float wsum[4];
    int S = blockIdx.x >> 3, sub = blockIdx.x & 7;
    int tid = threadIdx.x, lane = tid & 63, wv = tid >> 6;
    if (tid < 128) rws[tid] = rW[tid];
    __syncthreads();
    float acc = 0.f;
    for (int r = sub*400 + wv; r < (sub+1)*400; r += 4){
        size_t row = (size_t)S*PER*32 + r;
        float rad = radn[row];
        if (rad != 0.f){
            const float* xr = X + row*D;
            const float* yr = Y + row*D;
            acc += rad * ((xr[lane]+yr[lane])*rws[lane] + (xr[lane+64]+yr[lane+64])*rws[lane+64]);
        }
    }
    if (sub == 0){
        for (int nl = tid; nl < PER; nl += 256) acc += cw[ELEM[S*PER + nl]];
    }
    #pragma unroll
    for (int m = 1; m < 64; m <<= 1) acc += __shfl_xor(acc, m);
    if (lane == 0) wsum[wv] = acc;
    __syncthreads();
    if (tid == 0) atomicAdd(&out[S], wsum[0]+wsum[1]+wsum[2]+wsum[3]);
}

extern "C" void kernel_launch(void* const* d_in, const int* in_sizes, int n_in,
                              void* d_out, int out_size, void* d_ws, size_t ws_size,
                              hipStream_t stream){
    const float* positions   = (const float*)d_in[0];
    const float* cells       = (const float*)d_in[1];
    const float* cell_shifts = (const float*)d_in[2];
    const float* enc_Wcart   = (const float*)d_in[3];
    const float* enc_emb_c   = (const float*)d_in[4];
    const float* enc_emb_n   = (const float*)d_in[5];
    const float* enc_Wcomp   = (const float*)d_in[6];
    const float* t_Wq  = (const float*)d_in[7];
    const float* t_Wk  = (const float*)d_in[8];
    const float* t_Wv  = (const float*)d_in[9];
    const float* t_Wo  = (const float*)d_in[10];
    const float* t_ln1w = (const float*)d_in[11];
    const float* t_ln1b = (const float*)d_in[12];
    const float* t_ln2w = (const float*)d_in[13];
    const float* t_ln2b = (const float*)d_in[14];
    const float* t_W1  = (const float*)d_in[15];
    const float* t_b1  = (const float*)d_in[16];
    const float* t_W2  = (const float*)d_in[17];
    const float* t_b2  = (const float*)d_in[18];
    const float* g_contr = (const float*)d_in[19];
    const float* g_Wq  = (const float*)d_in[20];
    const float* g_Wk  = (const float*)d_in[21];
    const float* g_Wv  = (const float*)d_in[22];
    const float* g_Wo  = (const float*)d_in[23];
    const float* g_ln1w = (const float*)d_in[24];
    const float* g_ln1b = (const float*)d_in[25];
    const float* g_ln2w = (const float*)d_in[26];
    const float* g_ln2b = (const float*)d_in[27];
    const float* g_W1  = (const float*)d_in[28];
    const float* g_b1  = (const float*)d_in[29];
    const float* g_W2  = (const float*)d_in[30];
    const float* g_b2  = (const float*)d_in[31];
    const float* readout_W = (const float*)d_in[32];
    const float* comp_w    = (const float*)d_in[33];
    const int* numbers   = (const int*)d_in[34];
    const int* centers   = (const int*)d_in[35];
    const int* neighbors = (const int*)d_in[36];

    float* ws = (float*)d_ws;
    float* X    = ws;                       // NTOK*D
    float* Y    = X + (size_t)NTOK*D;       // NTOK*D
    float* EV   = Y + (size_t)NTOK*D;       // N_EDGES*3
    float* RAD  = EV + (size_t)N_EDGES*3;   // N_EDGES
    float* RADN = RAD + N_EDGES;            // NTOK
    float* W3   = RADN + NTOK;              // 3*128
    float* ECn  = W3 + 3*128;               // 4*128
    float* ENn  = ECn + 4*128;              // 4*128
    int*   ELEM = (int*)(ENn + 4*128);      // N_NODES
    int*   CORR = ELEM + N_NODES;           // N_EDGES
    short* WT   = (short*)(CORR + N_EDGES); // 819200 bf16 elems

    const short *tWqt = WT,           *tWkt = WT + 32768, *tWvt = WT + 65536, *tWot = WT + 98304;
    const short *tW1t = WT + 131072,  *tW2t = WT + 262144;
    const short *gWqt = WT + 393216,  *gWkt = WT + 425984, *gWvt = WT + 458752, *gWot = WT + 491520;
    const short *gW1t = WT + 524288,  *gW2t = WT + 655360, *gctT = WT + 786432;

    k_zero<<<1, 64, 0, stream>>>((float*)d_out);
    k_elem<<<(N_NODES+255)/256, 256, 0, stream>>>(numbers, ELEM);
    k_prep<<<1, 128, 0, stream>>>(enc_Wcart, enc_emb_c, enc_emb_n, enc_Wcomp, W3, ECn, ENn);
    k_wt<<<3200, 256, 0, stream>>>(t_Wq, t_Wk, t_Wv, t_Wo, t_W1, t_W2,
                                   g_Wq, g_Wk, g_Wv, g_Wo, g_W1, g_W2, g_contr, WT);
    k_edge<<<(N_EDGES+255)/256, 256, 0, stream>>>(positions, cells, cell_shifts, centers, neighbors, EV, RAD, CORR);
    k_encode<<<NTOK, 128, 0, stream>>>(EV, RAD, centers, neighbors, ELEM, W3, ECn, ENn, X, RADN);

    for (int l = 0; l < 2; l++){
        k_attn_mfma<<<N_NODES, 256, 0, stream>>>(X, tWqt + l*16384, tWkt + l*16384,
                                                 tWvt + l*16384, tWot + l*16384,
                                                 t_ln1w + l*128, t_ln1b + l*128, RADN);
        k_ffn_mfma<<<NTOK/32, 256, 0, stream>>>(X, tW1t + l*65536, tW2t + l*65536,
                                                t_b1 + l*512, t_b2 + l*128,
                                                t_ln2w + l*128, t_ln2b + l*128);
    }

    k_contract_mfma<<<N_EDGES/32, 256, 0, stream>>>(X, centers, CORR, gctT, Y);
    k_padfill<<<(N_NODES*8*D+255)/256, 256, 0, stream>>>(Y);

    for (int l = 0; l < 2; l++){
        k_attn_mfma<<<N_NODES, 256, 0, stream>>>(Y, gWqt + l*16384, gWkt + l*16384,
                                                 gWvt + l*16384, gWot + l*16384,
                                                 g_ln1w + l*128, g_ln1b + l*128, RADN);
        k_ffn_mfma<<<NTOK/32, 256, 0, stream>>>(Y, gW1t + l*65536, gW2t + l*65536,
                                                g_b1 + l*512, g_b2 + l*128,
                                                g_ln2w + l*128, g_ln2b + l*128);
    }

    k_readout<<<N_STRUCT*8, 256, 0, stream>>>(X, Y, readout_W, RADN, ELEM, comp_w, (float*)d_out);
}